// Round 3
// baseline (303.019 us; speedup 1.0000x reference)
//
#include <hip/hip_runtime.h>
#include <cstdint>
#include <cstddef>

#define IN_F 4096
#define OUT_F 4096
#define NROWS 8192
#define BM 256
#define BN 256
#define BK 32
#define NT (IN_F / BK)   // 128 K-tiles

typedef float f32x4 __attribute__((ext_vector_type(4)));
typedef float f32x16 __attribute__((ext_vector_type(16)));
typedef short s16x8 __attribute__((ext_vector_type(8)));

// round-to-nearest-even fp32 -> bf16
__device__ inline unsigned short f2bf_rne(float f) {
    unsigned int u = __float_as_uint(f);
    u += 0x7FFFu + ((u >> 16) & 1u);
    return (unsigned short)(u >> 16);
}

// Fused: blocks [0, 8192) build W; blocks [8192, 24576) convert x to bf16.
// w[o][t] = 2*norm(o)*sin(pi*(o+1)*(2t+1)/8192); integer-exact reduction mod 16384.
__global__ void prep(const float* __restrict__ x, const float* __restrict__ fc,
                     unsigned short* __restrict__ wb, unsigned short* __restrict__ xb) {
    const int b = blockIdx.x;
    if (b < OUT_F * IN_F / 8 / 256) {
        int gid = b * 256 + threadIdx.x;
        int o = gid >> 9;
        int t0 = (gid & 511) << 3;
        int k = (int)fc[o];
        float amp = 2.0f * rsqrtf(2.0f * (float)IN_F * ((k == 0) ? 2.0f : 1.0f));
        unsigned int op1 = (unsigned int)(k + 1);
        union { s16x8 v; unsigned short s[8]; } p;
#pragma unroll
        for (int j = 0; j < 8; ++j) {
            unsigned int t = (unsigned int)(t0 + j);
            unsigned int r = (op1 * (2u * t + 1u)) & 16383u;
            float ang = (float)r * 3.83495196971410293e-4f;  // pi/8192
            p.s[j] = f2bf_rne(amp * __sinf(ang));
        }
        *reinterpret_cast<s16x8*>(&wb[(size_t)gid * 8]) = p.v;
    } else {
        size_t gid = (size_t)(b - OUT_F * IN_F / 8 / 256) * 256 + threadIdx.x;
        const f32x4* xv = reinterpret_cast<const f32x4*>(x) + gid * 2;
        f32x4 a = xv[0], c = xv[1];
        union { s16x8 v; unsigned short s[8]; } p;
        p.s[0] = f2bf_rne(a[0]); p.s[1] = f2bf_rne(a[1]);
        p.s[2] = f2bf_rne(a[2]); p.s[3] = f2bf_rne(a[3]);
        p.s[4] = f2bf_rne(c[0]); p.s[5] = f2bf_rne(c[1]);
        p.s[6] = f2bf_rne(c[2]); p.s[7] = f2bf_rne(c[3]);
        *reinterpret_cast<s16x8*>(&xb[gid * 8]) = p.v;
    }
}

__device__ inline void wg_barrier() {
    asm volatile("" ::: "memory");
    __builtin_amdgcn_s_barrier();
    asm volatile("" ::: "memory");
}

#define GLD(gsrc, ldst) __builtin_amdgcn_global_load_lds( \
    (const __attribute__((address_space(1))) unsigned int*)(gsrc), \
    (__attribute__((address_space(3))) unsigned int*)(ldst), 16, 0, 0)

#define STAGE_A(T) do { \
    const int _sb = ((T) & 3) * 32768; \
    const int _sk = (T) * BK; \
    GLD(gA + _sk, (char*)lds + _sb + ldsA0); \
    GLD(gA2 + _sk, (char*)lds + _sb + ldsA1); \
} while (0)

#define STAGE_B(T) do { \
    const int _sb = ((T) & 3) * 32768; \
    const int _sk = (T) * BK; \
    GLD(gB + _sk, (char*)lds + _sb + ldsB0); \
    GLD(gB2 + _sk, (char*)lds + _sb + ldsB1); \
} while (0)

#define MFMA32(d, a, b) d = __builtin_amdgcn_mfma_f32_32x32x16_bf16(a, b, d, 0, 0, 0)
#define LD_AS(name, off) s16x8 name = *(const s16x8*)((const char*)lds + (off))

// One K-tile (BK=32) = 2 phases (kstep 0/1), each: 6 ds_read_b128 || stage ||
// barrier || lgkm(0) || 8 x mfma_32x32x16 || [counted vmcnt] || barrier.
#define TILE(T, DO_STAGE, VM) do { \
    { \
        const int _bb = ((T) & 3) * 32768; \
        const int _ax = _bb + aoff; \
        const int _bx = _bb + boff; \
        LD_AS(a0, _ax + 0); \
        LD_AS(a1, _ax + 2048); \
        LD_AS(a2, _ax + 4096); \
        LD_AS(a3, _ax + 6144); \
        LD_AS(b0, _bx + 0); \
        LD_AS(b1, _bx + 2048); \
        if (DO_STAGE) STAGE_A((T) + 3); \
        wg_barrier(); \
        asm volatile("s_waitcnt lgkmcnt(0)" ::: "memory"); \
        __builtin_amdgcn_sched_barrier(0); \
        __builtin_amdgcn_s_setprio(1); \
        MFMA32(acc[0][0], a0, b0); MFMA32(acc[0][1], a0, b1); \
        MFMA32(acc[1][0], a1, b0); MFMA32(acc[1][1], a1, b1); \
        MFMA32(acc[2][0], a2, b0); MFMA32(acc[2][1], a2, b1); \
        MFMA32(acc[3][0], a3, b0); MFMA32(acc[3][1], a3, b1); \
        __builtin_amdgcn_s_setprio(0); \
        wg_barrier(); \
    } \
    { \
        const int _bb = ((T) & 3) * 32768; \
        const int _ax = (_bb + aoff) ^ 32; \
        const int _bx = (_bb + boff) ^ 32; \
        LD_AS(a0, _ax + 0); \
        LD_AS(a1, _ax + 2048); \
        LD_AS(a2, _ax + 4096); \
        LD_AS(a3, _ax + 6144); \
        LD_AS(b0, _bx + 0); \
        LD_AS(b1, _bx + 2048); \
        if (DO_STAGE) STAGE_B((T) + 3); \
        wg_barrier(); \
        asm volatile("s_waitcnt lgkmcnt(0)" ::: "memory"); \
        __builtin_amdgcn_sched_barrier(0); \
        __builtin_amdgcn_s_setprio(1); \
        MFMA32(acc[0][0], a0, b0); MFMA32(acc[0][1], a0, b1); \
        MFMA32(acc[1][0], a1, b0); MFMA32(acc[1][1], a1, b1); \
        MFMA32(acc[2][0], a2, b0); MFMA32(acc[2][1], a2, b1); \
        MFMA32(acc[3][0], a3, b0); MFMA32(acc[3][1], a3, b1); \
        __builtin_amdgcn_s_setprio(0); \
        asm volatile("s_waitcnt vmcnt(" #VM ")" ::: "memory"); \
        wg_barrier(); \
    } \
} while (0)

__global__ __launch_bounds__(512, 2) void gemm_dst(
        const unsigned short* __restrict__ xb, const unsigned short* __restrict__ wb,
        const float* __restrict__ bias, float* __restrict__ out) {
    // 4-deep circular buffer: [buf][A 16KB | B 16KB] = 128 KB
    __shared__ unsigned short lds[65536];

    const int tid = threadIdx.x;
    const int lane = tid & 63;
    const int wave = tid >> 6;
    const int wave_m = wave >> 2;   // 0..1 -> 128-row half
    const int wave_n = wave & 3;    // 0..3 -> 64-col quarter
    const int rl = lane & 31;       // row within 32-row fragment
    const int kh = lane >> 5;       // k-half (8 elems each)

    const int bid = blockIdx.x;
    // XCD swizzle: 512 wgs, 64 per XCD; within XCD, 16 consecutive share the A row-panel
    const int swz = (bid & 7) * 64 + (bid >> 3);
    const int brow = (swz >> 4) * BM;   // 32 row panels
    const int bcol = (swz & 15) * BN;   // 16 col panels

    // ---- stage addressing (unchanged, proven 0-conflict): LDS granule p=tid holds
    // tile element (row=p>>2, col c = (p&3) ^ ((row>>1)&3)) ----
    const int srow = tid >> 2;
    const int skq = (tid & 3) ^ ((tid >> 3) & 3);
    const unsigned short* gA  = xb + (size_t)(brow + srow) * IN_F + skq * 8;
    const unsigned short* gA2 = gA + (size_t)128 * IN_F;
    const unsigned short* gB  = wb + (size_t)(bcol + srow) * IN_F + skq * 8;
    const unsigned short* gB2 = gB + (size_t)128 * IN_F;
    const int ldsA0 = tid * 16;
    const int ldsA1 = tid * 16 + 8192;
    const int ldsB0 = tid * 16 + 16384;
    const int ldsB1 = tid * 16 + 24576;

    // ---- ds_read addressing: granule (r, c'=c^((r>>1)&3)); c = kstep*2 + kh ----
    const int X = (rl >> 1) & 3;
    const int sw = ((kh ^ X) << 4);                       // kstep0; kstep1 = ^32
    const int aoff = (wave_m * 128 + rl) * 64 + sw;       // + m*2048
    const int boff = 16384 + (wave_n * 64 + rl) * 64 + sw; // + n*2048

    f32x16 acc[4][2];
#pragma unroll
    for (int m = 0; m < 4; ++m)
#pragma unroll
        for (int n = 0; n < 2; ++n)
            acc[m][n] = (f32x16)(0.f);

    // ---- prologue: stage tiles 0,1,2 (12 loads/wave); retire tile 0 ----
    STAGE_A(0); STAGE_B(0);
    STAGE_A(1); STAGE_B(1);
    STAGE_A(2); STAGE_B(2);
    asm volatile("s_waitcnt vmcnt(8)" ::: "memory");
    wg_barrier();

    // ---- main loop: compute buf[t&3], stage tile t+3 into buf[(t+3)&3] ----
#pragma unroll 4
    for (int t = 0; t < NT - 4; ++t) {   // 124 iters
        TILE(t, 1, 8);
    }
    TILE(NT - 4, 1, 8);                  // t=124, stages tile 127
    // ---- tail: drain 8 -> 4 -> 0 ----
    TILE(NT - 3, 0, 4);
    TILE(NT - 2, 0, 0);
    TILE(NT - 1, 0, 0);

    // ---- epilogue: C = acc + bias; 32x32 D layout: col=lane&31,
    // row=(reg&3)+8*(reg>>2)+4*(lane>>5) ----
    const int ccol0 = bcol + wave_n * 64 + rl;
    const int crow0 = brow + wave_m * 128 + 4 * kh;
    const float bv0 = bias[ccol0];
    const float bv1 = bias[ccol0 + 32];
#pragma unroll
    for (int m = 0; m < 4; ++m) {
#pragma unroll
        for (int r = 0; r < 16; ++r) {
            const int row = crow0 + m * 32 + (r & 3) + 8 * (r >> 2);
            float* orow = out + (size_t)row * OUT_F + ccol0;
            orow[0]  = acc[m][0][r] + bv0;
            orow[32] = acc[m][1][r] + bv1;
        }
    }
}

// last-resort fallback if workspace is too small (naive on-the-fly DST)
__global__ void fallback_kernel(const float* __restrict__ x, const float* __restrict__ fc,
                                const float* __restrict__ bias, float* __restrict__ out) {
    __shared__ float xrow[IN_F];
    const int o = blockIdx.x * 256 + threadIdx.x;
    const int n = blockIdx.y;
    for (int i = threadIdx.x; i < IN_F; i += 256)
        xrow[i] = x[(size_t)n * IN_F + i];
    __syncthreads();
    const int k = (int)fc[o];
    const float amp = 2.0f * rsqrtf(2.0f * (float)IN_F * ((k == 0) ? 2.0f : 1.0f));
    const unsigned int op1 = (unsigned int)(k + 1);
    float s = 0.f;
    for (int t = 0; t < IN_F; ++t) {
        unsigned int r = (op1 * (2u * (unsigned int)t + 1u)) & 16383u;
        s += xrow[t] * __sinf((float)r * 3.83495196971410293e-4f);
    }
    out[(size_t)n * OUT_F + o] = amp * s + bias[o];
}

extern "C" void kernel_launch(void* const* d_in, const int* in_sizes, int n_in,
                              void* d_out, int out_size, void* d_ws, size_t ws_size,
                              hipStream_t stream) {
    const float* x    = (const float*)d_in[0];
    const float* fc   = (const float*)d_in[1];
    const float* bias = (const float*)d_in[2];
    float* out = (float*)d_out;

    const size_t WBYTES = (size_t)OUT_F * IN_F * 2;   // 32 MB
    const size_t XBYTES = (size_t)NROWS * IN_F * 2;   // 64 MB

    if (ws_size >= WBYTES + XBYTES) {
        unsigned short* wb = (unsigned short*)d_ws;
        unsigned short* xb = (unsigned short*)((char*)d_ws + WBYTES);
        const int wgrid = OUT_F * IN_F / 8 / 256;           // 8192
        const int xgrid = NROWS * IN_F / 8 / 256;           // 16384
        prep<<<wgrid + xgrid, 256, 0, stream>>>(x, fc, wb, xb);
        const int grid = (NROWS / BM) * (OUT_F / BN);       // 512
        gemm_dst<<<grid, 512, 0, stream>>>(xb, wb, bias, out);
    } else {
        dim3 g(OUT_F / 256, NROWS);
        fallback_kernel<<<g, 256, 0, stream>>>(x, fc, bias, out);
    }
}